// Round 12
// baseline (25472.153 us; speedup 1.0000x reference)
//
#include <hip/hip_runtime.h>

#define HDIM 512
#define BATCH 32
#define SEQ 128
#define VOCAB 16384
#define NBLK 256
#define NGRU 128          // GRU blocks: j = blk*4 + wave (R8-proven spread)
#define NTHR 256
#define SLOTP 32          // u32s per 128B flag line
#define HLDS_W 516        // padded LDS row (4-way conflicts only)

typedef unsigned long long u64;
typedef unsigned int u32;

// ---------------- MALL agent-relaxed accessors (validated R5/R6/R8) ----------------
static __device__ __forceinline__ u64 aload64(const u64* p) {
    return __hip_atomic_load(p, __ATOMIC_RELAXED, __HIP_MEMORY_SCOPE_AGENT);
}
static __device__ __forceinline__ void astore64(u64* p, u64 v) {
    __hip_atomic_store(p, v, __ATOMIC_RELAXED, __HIP_MEMORY_SCOPE_AGENT);
}
static __device__ __forceinline__ u32 aload32(const u32* p) {
    return __hip_atomic_load(p, __ATOMIC_RELAXED, __HIP_MEMORY_SCOPE_AGENT);
}
static __device__ __forceinline__ void astore32(u32* p, u32 v) {
    __hip_atomic_store(p, v, __ATOMIC_RELAXED, __HIP_MEMORY_SCOPE_AGENT);
}
static __device__ __forceinline__ void astore32f(float* p, float v) {
    __hip_atomic_store((u32*)p, __float_as_uint(v), __ATOMIC_RELAXED,
                       __HIP_MEMORY_SCOPE_AGENT);
}

static __device__ __forceinline__ float4 ld4(const float* p) {
    return *reinterpret_cast<const float4*>(p);
}
static __device__ __forceinline__ float dot4(float4 a, float4 b) {
    return a.x*b.x + a.y*b.y + a.z*b.z + a.w*b.w;
}
static __device__ __forceinline__ u32 ford(float f) {   // monotone float->u32
    u32 b = __float_as_uint(f);
    return b ^ ((b >> 31) ? 0xFFFFFFFFu : 0x80000000u);
}
static __device__ __forceinline__ u64 shfl_xor_u64(u64 x, int m) {
    int lo = __shfl_xor((int)(u32)x, m);
    int hi = __shfl_xor((int)(u32)(x >> 32), m);
    return ((u64)(u32)hi << 32) | (u32)lo;
}

// ---- poll nslots per-block flag lines (read-only, first wave only) ----
static __device__ __forceinline__ void pollN(const u32* slots, u32 target,
                                             int tid, int nslots) {
    if (tid < 64) {
        const int per = (nslots + 63) >> 6;
        int it = 0;
        for (;;) {
            bool ok = true;
            for (int k = 0; k < per; ++k) {
                int idx = tid * per + k;
                if (idx < nslots)
                    ok &= (aload32(&slots[idx * SLOTP]) >= target);
            }
            if (__ballot(ok) == ~0ull) break;
            if (it > 64)      __builtin_amdgcn_s_sleep(16);
            else if (it > 8)  __builtin_amdgcn_s_sleep(2);
            ++it;
        }
    }
    __syncthreads();
    asm volatile("" ::: "memory");
}

// ---- stage 64KB h from MALL into LDS: wide sc1 loads (R8-proven, no rotation) ----
static __device__ __forceinline__ void stage_wide(float* hlf, const float* hsrc, int tid) {
    #pragma unroll
    for (int g = 0; g < 2; ++g) {
        float4 v[8];
        #pragma unroll
        for (int k = 0; k < 8; ++k) {
            int q = (g * 8 + k) * NTHR + tid;            // float4 index
            asm volatile("global_load_dwordx4 %0, %1, off sc1"
                         : "=v"(v[k]) : "v"(hsrc + q * 4));
        }
        asm volatile("s_waitcnt vmcnt(0)" ::: "memory");
        __builtin_amdgcn_sched_barrier(0);
        #pragma unroll
        for (int k = 0; k < 8; ++k) {
            int q = (g * 8 + k) * NTHR + tid;
            int w = q * 4;
            *reinterpret_cast<float4*>(hlf + (w >> 9) * HLDS_W + (w & 511)) = v[k];
        }
    }
}

// ---- stage via relaxed-atomic u64 (fallback kernels only; R6-proven) ----
static __device__ __forceinline__ void stage_h(float* hlf, const float* hglob, int tid) {
    const u64* src = (const u64*)hglob;
    #pragma unroll
    for (int it = 0; it < 32; ++it) {
        int q = it * 256 + tid;
        int w = q * 2;
        u64 v = aload64(src + q);
        *reinterpret_cast<u64*>(hlf + (w >> 9) * HLDS_W + (w & 511)) = v;
    }
}

// ---- GRU for one j: bit-identical arithmetic since round 1 ----
static __device__ __forceinline__ void gru_j(
    int j, int tid, const int* toks, const float* hlf, float* hout,
    const float* __restrict__ Wih, const float* __restrict__ Whh,
    const float* __restrict__ bih, const float* __restrict__ bhh,
    const float* __restrict__ emb)
{
    const int lane = tid & 63;
    const int kh   = lane >> 5;
    const int b    = lane & 31;

    const int tok = toks[b];
    const float* xrow = emb + (size_t)tok * HDIM + kh * 256;
    const float* hrow = hlf + b * HLDS_W + kh * 256;
    const float* wir = Wih + (size_t)(0*HDIM + j) * HDIM + kh * 256;
    const float* wiz = Wih + (size_t)(1*HDIM + j) * HDIM + kh * 256;
    const float* win = Wih + (size_t)(2*HDIM + j) * HDIM + kh * 256;
    const float* whr = Whh + (size_t)(0*HDIM + j) * HDIM + kh * 256;
    const float* whz = Whh + (size_t)(1*HDIM + j) * HDIM + kh * 256;
    const float* whn = Whh + (size_t)(2*HDIM + j) * HDIM + kh * 256;

    float pr = 0.f, pz = 0.f, pxn = 0.f, phn = 0.f;
    #pragma unroll 4
    for (int k4 = 0; k4 < 64; ++k4) {
        float4 x4 = ld4(xrow + k4*4);
        float4 h4 = ld4(hrow + k4*4);
        pr  += dot4(x4, ld4(wir + k4*4)) + dot4(h4, ld4(whr + k4*4));
        pz  += dot4(x4, ld4(wiz + k4*4)) + dot4(h4, ld4(whz + k4*4));
        pxn += dot4(x4, ld4(win + k4*4));
        phn += dot4(h4, ld4(whn + k4*4));
    }
    pr  += __shfl_xor(pr, 32);
    pz  += __shfl_xor(pz, 32);
    pxn += __shfl_xor(pxn, 32);
    phn += __shfl_xor(phn, 32);

    if (kh == 0) {
        float r = 1.f / (1.f + expf(-(pr + bih[j]      + bhh[j])));
        float z = 1.f / (1.f + expf(-(pz + bih[HDIM+j] + bhh[HDIM+j])));
        float n = tanhf(pxn + bih[2*HDIM+j] + r * (phn + bhh[2*HDIM+j]));
        float hprev = hlf[b * HLDS_W + j];
        astore32f(hout + b * HDIM + j, (1.f - z) * n + z * hprev);
    }
}

// ---- argmax finalize (256 pk partials -> 32 tokens); 256 threads; R6-proven ----
static __device__ __forceinline__ void argmax_finalize(
    int tid, const u64* pk, u64 (*redk)[8], int* tok_s)
{
    const int fb = tid >> 3, kc = tid & 7;
    const u64* p = pk + fb * NBLK;
    u64 best = aload64(p + kc);
    #pragma unroll 4
    for (int k = 1; k < 32; ++k) {
        u64 x = aload64(p + kc + k * 8);
        if (x > best) best = x;
    }
    redk[fb][kc] = best;
    __syncthreads();
    if (tid < BATCH) {
        u64 bb = redk[tid][0];
        #pragma unroll
        for (int c = 1; c < 8; ++c) { u64 x = redk[tid][c]; if (x > bb) bb = x; }
        tok_s[tid] = (int)(~(u32)bb);
    }
}

// ---- log_softmax row (256 threads) ----
static __device__ __forceinline__ void softmax_row(float* p, int tid,
                                                   float* redm, float* reds) {
    float4 vals[16];
    float m = -3.4e38f;
    #pragma unroll
    for (int i = 0; i < 16; ++i) {
        vals[i] = ld4(p + (i * 256 + tid) * 4);
        m = fmaxf(m, fmaxf(fmaxf(vals[i].x, vals[i].y), fmaxf(vals[i].z, vals[i].w)));
    }
    #pragma unroll
    for (int d = 1; d < 64; d <<= 1) m = fmaxf(m, __shfl_xor(m, d));
    if ((tid & 63) == 0) redm[tid >> 6] = m;
    __syncthreads();
    m = fmaxf(fmaxf(redm[0], redm[1]), fmaxf(redm[2], redm[3]));
    float s = 0.f;
    #pragma unroll
    for (int i = 0; i < 16; ++i) {
        s += expf(vals[i].x - m) + expf(vals[i].y - m)
           + expf(vals[i].z - m) + expf(vals[i].w - m);
    }
    #pragma unroll
    for (int d = 1; d < 64; d <<= 1) s += __shfl_xor(s, d);
    if ((tid & 63) == 0) reds[tid >> 6] = s;
    __syncthreads();
    s = reds[0] + reds[1] + reds[2] + reds[3];
    const float lg = m + logf(s);
    #pragma unroll
    for (int i = 0; i < 16; ++i) {
        float4 r;
        r.x = vals[i].x - lg; r.y = vals[i].y - lg;
        r.z = vals[i].z - lg; r.w = vals[i].w - lg;
        *reinterpret_cast<float4*>(p + (i * 256 + tid) * 4) = r;
    }
    __syncthreads();
}

// ==================== persistent cooperative kernel ====================
__global__ __launch_bounds__(NTHR, 1) void seq2seq_main(
    const int* __restrict__ input,
    const float* __restrict__ enc_emb, const float* __restrict__ enc_Wih,
    const float* __restrict__ enc_Whh, const float* __restrict__ enc_bih,
    const float* __restrict__ enc_bhh,
    const float* __restrict__ dec_emb, const float* __restrict__ dec_Wih,
    const float* __restrict__ dec_Whh, const float* __restrict__ dec_bih,
    const float* __restrict__ dec_bhh,
    const float* __restrict__ out_W, const float* __restrict__ out_b,
    float* __restrict__ out, float* hglob, u64* pk,
    u32* hslot, u32* pkslot)
{
    __shared__ __align__(16) float hl[BATCH][HLDS_W];   // 66048 B
    __shared__ int tok_s[BATCH];
    __shared__ u64 redk[BATCH][8];

    const int tid = threadIdx.x;
    const int blk = blockIdx.x;
    float* hlf = &hl[0][0];

    // hlf = h(0) = 0 (encoder step 0 input)
    for (int i = tid; i < BATCH * HLDS_W; i += NTHR) hlf[i] = 0.f;
    __syncthreads();

    const int w = tid >> 6;          // wave 0..3
    const int vloc = tid & 63;
    const int v    = blk * 64 + vloc;            // this thread's vocab row
    const float* wrow = out_W + (size_t)v * HDIM;

    // ---------------- encoder: 128 steps (blocks 0..127 only) ----------------
    if (blk < NGRU) {
        for (int t = 0; t < SEQ; ++t) {
            float* hgo = hglob + ((t + 1) & 1) * (BATCH * HDIM);
            if (tid < BATCH) tok_s[tid] = input[tid * SEQ + t];
            __syncthreads();
            gru_j(blk * 4 + w, tid, tok_s, hlf, hgo,
                  enc_Wih, enc_Whh, enc_bih, enc_bhh, enc_emb);
            __syncthreads();                          // drains all waves' stores
            if (tid == 0) astore32(&hslot[blk * SLOTP], (u32)(t + 1));
            pollN(hslot, (u32)(t + 1), tid, NGRU);    // h(t+1) @ MALL
            stage_wide(hlf, hgo, tid);                // hlf <- h(t+1)
            __syncthreads();
        }
    }

    // ---------------- decoder: 128 steps ----------------
    for (int t = 0; t < SEQ; ++t) {
        float* hgo = hglob + ((t + 1) & 1) * (BATCH * HDIM);

        if (blk < NGRU) {
            if (t == 0) {
                if (tid < BATCH) tok_s[tid] = 0;      // SOS
                __syncthreads();
            } else {
                pollN(pkslot, (u32)t, tid, NBLK);     // all 256 logits(t-1) done
                argmax_finalize(tid, pk, redk, tok_s);
                __syncthreads();
            }
            // hlf holds h(t); compute h(t+1)
            gru_j(blk * 4 + w, tid, tok_s, hlf, hgo,
                  dec_Wih, dec_Whh, dec_bih, dec_bhh, dec_emb);
            __syncthreads();
            if (tid == 0) astore32(&hslot[blk * SLOTP], (u32)(SEQ + t + 1));
        }

        // ---- R12: prefetch head of this thread's out_W stream; constants,
        //      so arithmetic is unchanged -- overlaps the poll + stage below.
        float4 pf[8];
        #pragma unroll
        for (int k4 = 0; k4 < 8; ++k4) pf[k4] = ld4(wrow + k4*4);

        pollN(hslot, (u32)(SEQ + t + 1), tid, NGRU);  // h(t+1) @ MALL
        stage_wide(hlf, hgo, tid);                    // hlf <- h(t+1)
        __syncthreads();

        // ---- logits (R8-proven register version, exact summation order):
        //      acc[q][i], q-loop unrolled, k4 sequential per (q,i). ----
        {
            const int bq = w;                         // batch group of 8

            float acc[4][8];
            #pragma unroll
            for (int q = 0; q < 4; ++q)
                #pragma unroll
                for (int i = 0; i < 8; ++i) acc[q][i] = 0.f;

            // q = 0: first 8 k4 chunks come from the prefetch registers
            for (int k4 = 0; k4 < 32; ++k4) {
                float4 w4 = (k4 < 8) ? pf[k4] : ld4(wrow + k4*4);
                #pragma unroll
                for (int i = 0; i < 8; ++i) {
                    float4 h4 = ld4(hlf + (bq*8 + i) * HLDS_W + k4*4);
                    acc[0][i] += dot4(w4, h4);
                }
            }
            #pragma unroll
            for (int q = 1; q < 4; ++q) {
                for (int k4 = 0; k4 < 32; ++k4) {
                    float4 w4 = ld4(wrow + q*128 + k4*4);
                    #pragma unroll
                    for (int i = 0; i < 8; ++i) {
                        float4 h4 = ld4(hlf + (bq*8 + i) * HLDS_W + q*128 + k4*4);
                        acc[q][i] += dot4(w4, h4);
                    }
                }
            }

            const float vbias = out_b[v];
            #pragma unroll
            for (int i = 0; i < 8; ++i) {
                const int b = bq*8 + i;
                float s = ((acc[0][i] + acc[1][i]) + acc[2][i]) + acc[3][i] + vbias;
                __builtin_nontemporal_store(s,
                    &out[(size_t)b*(SEQ*VOCAB) + (size_t)t*VOCAB + v]);
                u64 key = ((u64)ford(s) << 32) | (u32)(~(u32)v);
                #pragma unroll
                for (int d = 1; d < 64; d <<= 1) {
                    u64 o = shfl_xor_u64(key, d);
                    if (o > key) key = o;
                }
                if (vloc == 0) astore64(&pk[b * NBLK + blk], key);
            }
        }
        __syncthreads();                              // drain NT + pk stores
        if (tid == 0) astore32(&pkslot[blk * SLOTP], (u32)(t + 1));
    }

    // ---- final decoder hidden: hlf holds h(dec,128) on every block ----
    if (blk < 16) {
        const int idx = blk * 1024 + tid * 4;
        const int b = idx >> 9, j = idx & 511;
        *reinterpret_cast<float4*>(out + (size_t)BATCH * SEQ * VOCAB + idx) =
            *reinterpret_cast<const float4*>(&hl[b][j]);
    }
}

// ---- init: zero h0 + flag lines (ws not re-poisoned between replays) ----
__global__ __launch_bounds__(256) void init_kernel(float* __restrict__ h0,
                                                   u32* __restrict__ hslot,
                                                   u32* __restrict__ pkslot) {
    int i = blockIdx.x * 256 + threadIdx.x;
    if (i < BATCH * HDIM) h0[i] = 0.f;
    if (i < NGRU * SLOTP) hslot[i] = 0;
    if (i < NBLK * SLOTP) pkslot[i] = 0;
}

// ==================== fallback multi-kernel path (R6-proven, 256 thr) ====================
__global__ __launch_bounds__(256) void gru_step_fb(
    const float* __restrict__ h_in, float* __restrict__ h_out,
    const float* __restrict__ Wih, const float* __restrict__ Whh,
    const float* __restrict__ bih, const float* __restrict__ bhh,
    const float* __restrict__ emb,
    const int* __restrict__ enc_tokens, int t, const u64* __restrict__ pk)
{
    __shared__ __align__(16) float hlt[BATCH][HLDS_W];
    __shared__ int tok_s[BATCH];
    __shared__ u64 redk[BATCH][8];
    const int tid = threadIdx.x;

    if (enc_tokens != nullptr) {
        if (tid < BATCH) tok_s[tid] = enc_tokens[tid * SEQ + t];
    } else if (t == 0) {
        if (tid < BATCH) tok_s[tid] = 0;
    } else {
        argmax_finalize(tid, pk, redk, tok_s);
    }
    stage_h(&hlt[0][0], h_in, tid);
    __syncthreads();
    gru_j(blockIdx.x * 4 + (tid >> 6), tid, tok_s, &hlt[0][0], h_out,
          Wih, Whh, bih, bhh, emb);
}

__global__ __launch_bounds__(256) void logits_fb(
    const float* __restrict__ h, const float* __restrict__ outW,
    const float* __restrict__ outb, float* __restrict__ out,
    int t, u64* __restrict__ pk)
{
    __shared__ __align__(16) float hlt[BATCH][HLDS_W];
    const int tid = threadIdx.x;
    stage_h(&hlt[0][0], h, tid);
    __syncthreads();

    const int vloc = tid & 63;
    const int bq   = tid >> 6;
    const int v    = blockIdx.x * 64 + vloc;
    const float* wrow = outW + (size_t)v * HDIM;
    const float* hlf = &hlt[0][0];

    float acc[4][8];
    #pragma unroll
    for (int q = 0; q < 4; ++q)
        #pragma unroll
        for (int i = 0; i < 8; ++i) acc[q][i] = 0.f;
    #pragma unroll
    for (int q = 0; q < 4; ++q)
        for (int k4 = 0; k4 < 32; ++k4) {
            float4 w4 = ld4(wrow + q*128 + k4*4);
            #pragma unroll
            for (int i = 0; i < 8; ++i)
                acc[q][i] += dot4(w4, ld4(hlf + (bq*8 + i) * HLDS_W + q*128 + k4*4));
        }
    const float vbias = outb[v];
    #pragma unroll
    for (int i = 0; i < 8; ++i) {
        const int b = bq*8 + i;
        float s = ((acc[0][i] + acc[1][i]) + acc[2][i]) + acc[3][i] + vbias;
        out[(size_t)b * (SEQ * VOCAB) + (size_t)t * VOCAB + v] = s;
        u64 key = ((u64)ford(s) << 32) | (u32)(~(u32)v);
        #pragma unroll
        for (int d = 1; d < 64; d <<= 1) {
            u64 o = shfl_xor_u64(key, d);
            if (o > key) key = o;
        }
        if (vloc == 0) astore64(pk + b * NBLK + blockIdx.x, key);
    }
}

__global__ __launch_bounds__(256) void copy_fb(const float* __restrict__ src,
                                               float* __restrict__ dst, int n) {
    int i = blockIdx.x * 256 + threadIdx.x;
    if (i < n) dst[i] = src[i];
}

__global__ __launch_bounds__(256) void softmax_kernel(float* __restrict__ out) {
    __shared__ float redm[4];
    __shared__ float reds[4];
    softmax_row(out + (size_t)blockIdx.x * VOCAB, threadIdx.x, redm, reds);
}

extern "C" void kernel_launch(void* const* d_in, const int* in_sizes, int n_in,
                              void* d_out, int out_size, void* d_ws, size_t ws_size,
                              hipStream_t stream) {
    const int*   input    = (const int*)  d_in[0];
    const float* enc_emb  = (const float*)d_in[1];
    const float* enc_Wih  = (const float*)d_in[2];
    const float* enc_Whh  = (const float*)d_in[3];
    const float* enc_bih  = (const float*)d_in[4];
    const float* enc_bhh  = (const float*)d_in[5];
    const float* dec_emb  = (const float*)d_in[6];
    const float* dec_Wih  = (const float*)d_in[7];
    const float* dec_Whh  = (const float*)d_in[8];
    const float* dec_bih  = (const float*)d_in[9];
    const float* dec_bhh  = (const float*)d_in[10];
    const float* out_W    = (const float*)d_in[11];
    const float* out_b    = (const float*)d_in[12];

    float* out = (float*)d_out;
    char*  ws  = (char*)d_ws;

    float* hglob  = (float*)ws;                      // 2*16384 f = 131072 B
    u64*   pk     = (u64*)(ws + 131072);             // 8192 u64 = 65536 B
    u32*   hslot  = (u32*)(ws + 196608);             // 128 lines = 16384 B
    u32*   pkslot = (u32*)(ws + 212992);             // 256 lines = 32768 B

    init_kernel<<<dim3(64), dim3(256), 0, stream>>>(hglob, hslot, pkslot);

    void* args[] = {
        (void*)&input, (void*)&enc_emb, (void*)&enc_Wih, (void*)&enc_Whh,
        (void*)&enc_bih, (void*)&enc_bhh,
        (void*)&dec_emb, (void*)&dec_Wih, (void*)&dec_Whh, (void*)&dec_bih,
        (void*)&dec_bhh, (void*)&out_W, (void*)&out_b,
        (void*)&out, (void*)&hglob, (void*)&pk,
        (void*)&hslot, (void*)&pkslot
    };
    hipError_t rc = hipLaunchCooperativeKernel((void*)seq2seq_main,
                                               dim3(NBLK), dim3(NTHR),
                                               args, 0, stream);
    if (rc != hipSuccess) {
        // fallback: multi-kernel path (kernel boundaries provide ordering)
        float* hb[2] = { hglob, hglob + BATCH * HDIM };
        for (int t = 0; t < SEQ; ++t) {
            gru_step_fb<<<dim3(128), dim3(256), 0, stream>>>(
                hb[t & 1], hb[(t + 1) & 1],
                enc_Wih, enc_Whh, enc_bih, enc_bhh, enc_emb, input, t, nullptr);
        }
        for (int t = 0; t < SEQ; ++t) {
            gru_step_fb<<<dim3(128), dim3(256), 0, stream>>>(
                hb[t & 1], hb[(t + 1) & 1],
                dec_Wih, dec_Whh, dec_bih, dec_bhh, dec_emb, nullptr, t, pk);
            logits_fb<<<dim3(NBLK), dim3(256), 0, stream>>>(
                hb[(t + 1) & 1], out_W, out_b, out, t, pk);
        }
        copy_fb<<<dim3((BATCH * HDIM + 255) / 256), dim3(256), 0, stream>>>(
            hglob, out + (size_t)BATCH * SEQ * VOCAB, BATCH * HDIM);
    }

    softmax_kernel<<<dim3(BATCH * SEQ), dim3(256), 0, stream>>>(out);
}

// Round 13
// 10168.584 us; speedup vs baseline: 2.5050x; 2.5050x over previous
//
#include <hip/hip_runtime.h>

#define HDIM 512
#define BATCH 32
#define SEQ 128
#define VOCAB 16384
#define NBLK 256
#define NGRU 128          // GRU blocks: j = blk*4 + wave (R8-proven spread)
#define NTHR 256
#define SLOTP 32          // u32s per 128B flag line
#define HLDS_W 516        // padded LDS row (4-way conflicts only)

typedef unsigned long long u64;
typedef unsigned int u32;
typedef __attribute__((ext_vector_type(2))) unsigned long long u64x2;

// ---------------- MALL agent-relaxed accessors (validated R5/R6/R8) ----------------
static __device__ __forceinline__ u64 aload64(const u64* p) {
    return __hip_atomic_load(p, __ATOMIC_RELAXED, __HIP_MEMORY_SCOPE_AGENT);
}
static __device__ __forceinline__ void astore64(u64* p, u64 v) {
    __hip_atomic_store(p, v, __ATOMIC_RELAXED, __HIP_MEMORY_SCOPE_AGENT);
}
static __device__ __forceinline__ u32 aload32(const u32* p) {
    return __hip_atomic_load(p, __ATOMIC_RELAXED, __HIP_MEMORY_SCOPE_AGENT);
}
static __device__ __forceinline__ void astore32(u32* p, u32 v) {
    __hip_atomic_store(p, v, __ATOMIC_RELAXED, __HIP_MEMORY_SCOPE_AGENT);
}
static __device__ __forceinline__ void astore32f(float* p, float v) {
    __hip_atomic_store((u32*)p, __float_as_uint(v), __ATOMIC_RELAXED,
                       __HIP_MEMORY_SCOPE_AGENT);
}

static __device__ __forceinline__ float4 ld4(const float* p) {
    return *reinterpret_cast<const float4*>(p);
}
static __device__ __forceinline__ float dot4(float4 a, float4 b) {
    return a.x*b.x + a.y*b.y + a.z*b.z + a.w*b.w;
}
static __device__ __forceinline__ u32 ford(float f) {   // monotone float->u32
    u32 b = __float_as_uint(f);
    return b ^ ((b >> 31) ? 0xFFFFFFFFu : 0x80000000u);
}
static __device__ __forceinline__ u64 shfl_xor_u64(u64 x, int m) {
    int lo = __shfl_xor((int)(u32)x, m);
    int hi = __shfl_xor((int)(u32)(x >> 32), m);
    return ((u64)(u32)hi << 32) | (u32)lo;
}

// ---- poll nslots per-block flag lines (used only by aggregator blocks now) ----
static __device__ __forceinline__ void pollN(const u32* slots, u32 target,
                                             int tid, int nslots) {
    if (tid < 64) {
        const int per = (nslots + 63) >> 6;
        int it = 0;
        for (;;) {
            bool ok = true;
            for (int k = 0; k < per; ++k) {
                int idx = tid * per + k;
                if (idx < nslots)
                    ok &= (aload32(&slots[idx * SLOTP]) >= target);
            }
            if (__ballot(ok) == ~0ull) break;
            if (it > 64)      __builtin_amdgcn_s_sleep(16);
            else if (it > 8)  __builtin_amdgcn_s_sleep(2);
            ++it;
        }
    }
    __syncthreads();
    asm volatile("" ::: "memory");
}

// ---- poll a single go-line (R13: consumers read one line instead of scanning) ----
static __device__ __forceinline__ void poll1(const u32* line, u32 target, int tid) {
    if (tid == 0) {
        int it = 0;
        while (aload32(line) < target) {
            if (it > 64)      __builtin_amdgcn_s_sleep(16);
            else if (it > 8)  __builtin_amdgcn_s_sleep(2);
            ++it;
        }
    }
    __syncthreads();
    asm volatile("" ::: "memory");
}

// ---- stage 64KB h from MALL into LDS: wide sc1 loads (R8-proven) ----
static __device__ __forceinline__ void stage_wide(float* hlf, const float* hsrc, int tid) {
    #pragma unroll
    for (int g = 0; g < 2; ++g) {
        float4 v[8];
        #pragma unroll
        for (int k = 0; k < 8; ++k) {
            int q = (g * 8 + k) * NTHR + tid;            // float4 index
            asm volatile("global_load_dwordx4 %0, %1, off sc1"
                         : "=v"(v[k]) : "v"(hsrc + q * 4));
        }
        asm volatile("s_waitcnt vmcnt(0)" ::: "memory");
        __builtin_amdgcn_sched_barrier(0);
        #pragma unroll
        for (int k = 0; k < 8; ++k) {
            int q = (g * 8 + k) * NTHR + tid;
            int w = q * 4;
            *reinterpret_cast<float4*>(hlf + (w >> 9) * HLDS_W + (w & 511)) = v[k];
        }
    }
}

// ---- stage via relaxed-atomic u64 (fallback kernels only; R6-proven) ----
static __device__ __forceinline__ void stage_h(float* hlf, const float* hglob, int tid) {
    const u64* src = (const u64*)hglob;
    #pragma unroll
    for (int it = 0; it < 32; ++it) {
        int q = it * 256 + tid;
        int w = q * 2;
        u64 v = aload64(src + q);
        *reinterpret_cast<u64*>(hlf + (w >> 9) * HLDS_W + (w & 511)) = v;
    }
}

// ---- GRU for one j: bit-identical arithmetic since round 1 ----
static __device__ __forceinline__ void gru_j(
    int j, int tid, const int* toks, const float* hlf, float* hout,
    const float* __restrict__ Wih, const float* __restrict__ Whh,
    const float* __restrict__ bih, const float* __restrict__ bhh,
    const float* __restrict__ emb)
{
    const int lane = tid & 63;
    const int kh   = lane >> 5;
    const int b    = lane & 31;

    const int tok = toks[b];
    const float* xrow = emb + (size_t)tok * HDIM + kh * 256;
    const float* hrow = hlf + b * HLDS_W + kh * 256;
    const float* wir = Wih + (size_t)(0*HDIM + j) * HDIM + kh * 256;
    const float* wiz = Wih + (size_t)(1*HDIM + j) * HDIM + kh * 256;
    const float* win = Wih + (size_t)(2*HDIM + j) * HDIM + kh * 256;
    const float* whr = Whh + (size_t)(0*HDIM + j) * HDIM + kh * 256;
    const float* whz = Whh + (size_t)(1*HDIM + j) * HDIM + kh * 256;
    const float* whn = Whh + (size_t)(2*HDIM + j) * HDIM + kh * 256;

    float pr = 0.f, pz = 0.f, pxn = 0.f, phn = 0.f;
    #pragma unroll 4
    for (int k4 = 0; k4 < 64; ++k4) {
        float4 x4 = ld4(xrow + k4*4);
        float4 h4 = ld4(hrow + k4*4);
        pr  += dot4(x4, ld4(wir + k4*4)) + dot4(h4, ld4(whr + k4*4));
        pz  += dot4(x4, ld4(wiz + k4*4)) + dot4(h4, ld4(whz + k4*4));
        pxn += dot4(x4, ld4(win + k4*4));
        phn += dot4(h4, ld4(whn + k4*4));
    }
    pr  += __shfl_xor(pr, 32);
    pz  += __shfl_xor(pz, 32);
    pxn += __shfl_xor(pxn, 32);
    phn += __shfl_xor(phn, 32);

    if (kh == 0) {
        float r = 1.f / (1.f + expf(-(pr + bih[j]      + bhh[j])));
        float z = 1.f / (1.f + expf(-(pz + bih[HDIM+j] + bhh[HDIM+j])));
        float n = tanhf(pxn + bih[2*HDIM+j] + r * (phn + bhh[2*HDIM+j]));
        float hprev = hlf[b * HLDS_W + j];
        astore32f(hout + b * HDIM + j, (1.f - z) * n + z * hprev);
    }
}

// ---- logits core: exact R8 arithmetic (acc[4][8], q unrolled, k4 sequential) ----
static __device__ __forceinline__ void logits_core(
    int blk, int tid, const float* hlf,
    const float* __restrict__ outW, const float* __restrict__ outb,
    float* __restrict__ out, int t, u64* pk)
{
    const int vloc = tid & 63;
    const int bq   = tid >> 6;
    const int v    = blk * 64 + vloc;
    const float* wrow = outW + (size_t)v * HDIM;

    float acc[4][8];
    #pragma unroll
    for (int q = 0; q < 4; ++q)
        #pragma unroll
        for (int i = 0; i < 8; ++i) acc[q][i] = 0.f;

    #pragma unroll
    for (int q = 0; q < 4; ++q) {
        for (int k4 = 0; k4 < 32; ++k4) {
            float4 w4 = ld4(wrow + q*128 + k4*4);
            #pragma unroll
            for (int i = 0; i < 8; ++i) {
                float4 h4 = ld4(hlf + (bq*8 + i) * HLDS_W + q*128 + k4*4);
                acc[q][i] += dot4(w4, h4);
            }
        }
    }
    const float vbias = outb[v];
    #pragma unroll
    for (int i = 0; i < 8; ++i) {
        const int b = bq*8 + i;
        float s = ((acc[0][i] + acc[1][i]) + acc[2][i]) + acc[3][i] + vbias;
        __builtin_nontemporal_store(s, &out[(size_t)b*(SEQ*VOCAB) + (size_t)t*VOCAB + v]);
        u64 key = ((u64)ford(s) << 32) | (u32)(~(u32)v);
        #pragma unroll
        for (int d = 1; d < 64; d <<= 1) {
            u64 o = shfl_xor_u64(key, d);
            if (o > key) key = o;
        }
        if (vloc == 0) astore64(pk + b * NBLK + blk, key);
    }
}

// ---- argmax finalize (fallback path only; R6-proven) ----
static __device__ __forceinline__ void argmax_finalize(
    int tid, const u64* pk, u64 (*redk)[8], int* tok_s)
{
    const int fb = tid >> 3, kc = tid & 7;
    const u64* p = pk + fb * NBLK;
    u64 best = aload64(p + kc);
    #pragma unroll 4
    for (int k = 1; k < 32; ++k) {
        u64 x = aload64(p + kc + k * 8);
        if (x > best) best = x;
    }
    redk[fb][kc] = best;
    __syncthreads();
    if (tid < BATCH) {
        u64 bb = redk[tid][0];
        #pragma unroll
        for (int c = 1; c < 8; ++c) { u64 x = redk[tid][c]; if (x > bb) bb = x; }
        tok_s[tid] = (int)(~(u32)bb);
    }
}

// ---- log_softmax row (256 threads) ----
static __device__ __forceinline__ void softmax_row(float* p, int tid,
                                                   float* redm, float* reds) {
    float4 vals[16];
    float m = -3.4e38f;
    #pragma unroll
    for (int i = 0; i < 16; ++i) {
        vals[i] = ld4(p + (i * 256 + tid) * 4);
        m = fmaxf(m, fmaxf(fmaxf(vals[i].x, vals[i].y), fmaxf(vals[i].z, vals[i].w)));
    }
    #pragma unroll
    for (int d = 1; d < 64; d <<= 1) m = fmaxf(m, __shfl_xor(m, d));
    if ((tid & 63) == 0) redm[tid >> 6] = m;
    __syncthreads();
    m = fmaxf(fmaxf(redm[0], redm[1]), fmaxf(redm[2], redm[3]));
    float s = 0.f;
    #pragma unroll
    for (int i = 0; i < 16; ++i) {
        s += expf(vals[i].x - m) + expf(vals[i].y - m)
           + expf(vals[i].z - m) + expf(vals[i].w - m);
    }
    #pragma unroll
    for (int d = 1; d < 64; d <<= 1) s += __shfl_xor(s, d);
    if ((tid & 63) == 0) reds[tid >> 6] = s;
    __syncthreads();
    s = reds[0] + reds[1] + reds[2] + reds[3];
    const float lg = m + logf(s);
    #pragma unroll
    for (int i = 0; i < 16; ++i) {
        float4 r;
        r.x = vals[i].x - lg; r.y = vals[i].y - lg;
        r.z = vals[i].z - lg; r.w = vals[i].w - lg;
        *reinterpret_cast<float4*>(p + (i * 256 + tid) * 4) = r;
    }
    __syncthreads();
}

// ==================== persistent cooperative kernel ====================
__global__ __launch_bounds__(NTHR, 1) void seq2seq_main(
    const int* __restrict__ input,
    const float* __restrict__ enc_emb, const float* __restrict__ enc_Wih,
    const float* __restrict__ enc_Whh, const float* __restrict__ enc_bih,
    const float* __restrict__ enc_bhh,
    const float* __restrict__ dec_emb, const float* __restrict__ dec_Wih,
    const float* __restrict__ dec_Whh, const float* __restrict__ dec_bih,
    const float* __restrict__ dec_bhh,
    const float* __restrict__ out_W, const float* __restrict__ out_b,
    float* __restrict__ out, float* hglob, u64* pk,
    u32* hslot, u32* pkslot, u32* go_h, u32* go_pk, u64* tokline)
{
    __shared__ __align__(16) float hl[BATCH][HLDS_W];   // 66048 B
    __shared__ int tok_s[BATCH];

    const int tid = threadIdx.x;
    const int blk = blockIdx.x;
    float* hlf = &hl[0][0];

    // hlf = h(0) = 0 (encoder step 0 input)
    for (int i = tid; i < BATCH * HLDS_W; i += NTHR) hlf[i] = 0.f;
    __syncthreads();

    const int w = tid >> 6;          // wave 0..3

    // ---------------- encoder: 128 steps (GRU blocks + aggregator 255) ----------------
    if (blk < NGRU) {
        for (int t = 0; t < SEQ; ++t) {
            float* hgo = hglob + ((t + 1) & 1) * (BATCH * HDIM);
            if (tid < BATCH) tok_s[tid] = input[tid * SEQ + t];
            __syncthreads();
            gru_j(blk * 4 + w, tid, tok_s, hlf, hgo,
                  enc_Wih, enc_Whh, enc_bih, enc_bhh, enc_emb);
            __syncthreads();                          // drains stores (compiler waitcnt)
            if (tid == 0) astore32(&hslot[blk * SLOTP], (u32)(t + 1));
            poll1(go_h, (u32)(t + 1), tid);           // aggregated h-ready
            stage_wide(hlf, hgo, tid);                // hlf <- h(t+1)
            __syncthreads();
        }
    } else if (blk == 255) {
        for (int t = 0; t < SEQ; ++t) {
            pollN(hslot, (u32)(t + 1), tid, NGRU);    // scan 128 flags (only this block)
            if (tid == 0) astore32(go_h, (u32)(t + 1));
        }
    }

    // ---------------- decoder: 128 steps ----------------
    for (int t = 0; t < SEQ; ++t) {
        float* hgo = hglob + ((t + 1) & 1) * (BATCH * HDIM);

        if (blk < NGRU) {
            if (t == 0) {
                if (tid < BATCH) tok_s[tid] = 0;      // SOS
                __syncthreads();
            } else {
                // ---- R13 two-level argmax ----
                if (blk < BATCH) {                    // gatherer for row b = blk
                    poll1(go_pk, (u32)t, tid);        // all pk(t-1) flags seen by 254
                    if (tid < 64) {
                        const u64* prow = pk + (size_t)blk * NBLK + tid * 4;
                        u64x2 a, b2;
                        asm volatile("global_load_dwordx4 %0, %1, off sc1"
                                     : "=v"(a) : "v"(prow));
                        asm volatile("global_load_dwordx4 %0, %1, off sc1"
                                     : "=v"(b2) : "v"(prow + 2));
                        asm volatile("s_waitcnt vmcnt(0)" ::: "memory");
                        u64 best = a.x;
                        if (a.y  > best) best = a.y;
                        if (b2.x > best) best = b2.x;
                        if (b2.y > best) best = b2.y;
                        #pragma unroll
                        for (int d = 1; d < 64; d <<= 1) {
                            u64 o = shfl_xor_u64(best, d);
                            if (o > best) best = o;
                        }
                        if (tid == 0)
                            astore64(&tokline[blk * 16],
                                     ((u64)(u32)t << 32) | (u32)(~(u32)best));
                    }
                }
                // all GRU blocks: poll the 32 token lines (epoch t)
                if (tid < 64) {
                    u64 tv = 0; int it = 0;
                    for (;;) {
                        bool ok = true;
                        if (tid < 32) {
                            tv = aload64(&tokline[tid * 16]);
                            ok = ((u32)(tv >> 32) >= (u32)t);
                        }
                        if (__ballot(ok) == ~0ull) break;
                        if (it > 64)      __builtin_amdgcn_s_sleep(16);
                        else if (it > 8)  __builtin_amdgcn_s_sleep(2);
                        ++it;
                    }
                    if (tid < 32) tok_s[tid] = (int)(u32)tv;
                }
                __syncthreads();
            }
            // hlf holds h(t); compute h(t+1)
            gru_j(blk * 4 + w, tid, tok_s, hlf, hgo,
                  dec_Wih, dec_Whh, dec_bih, dec_bhh, dec_emb);
            __syncthreads();
            if (tid == 0) astore32(&hslot[blk * SLOTP], (u32)(SEQ + t + 1));
        }

        if (blk == 255) {
            pollN(hslot, (u32)(SEQ + t + 1), tid, NGRU);
            if (tid == 0) astore32(go_h, (u32)(SEQ + t + 1));
        } else {
            poll1(go_h, (u32)(SEQ + t + 1), tid);
        }
        stage_wide(hlf, hgo, tid);                    // hlf <- h(t+1)
        __syncthreads();
        logits_core(blk, tid, hlf, out_W, out_b, out, t, pk);
        __syncthreads();                              // drain NT + pk stores
        if (tid == 0) astore32(&pkslot[blk * SLOTP], (u32)(t + 1));
        if (blk == 254) {
            pollN(pkslot, (u32)(t + 1), tid, NBLK);   // scan 256 flags (only this block)
            if (tid == 0) astore32(go_pk, (u32)(t + 1));
        }
    }

    // ---- final decoder hidden: hlf holds h(dec,128) on every block ----
    if (blk < 16) {
        const int idx = blk * 1024 + tid * 4;
        const int b = idx >> 9, j = idx & 511;
        *reinterpret_cast<float4*>(out + (size_t)BATCH * SEQ * VOCAB + idx) =
            *reinterpret_cast<const float4*>(&hl[b][j]);
    }
}

// ---- init: zero h0 + all flag regions (ws not re-poisoned between replays) ----
__global__ __launch_bounds__(256) void init_kernel(float* __restrict__ h0,
                                                   u32* __restrict__ hslot,
                                                   u32* __restrict__ pkslot,
                                                   u32* __restrict__ extra) {
    int i = blockIdx.x * 256 + threadIdx.x;
    if (i < BATCH * HDIM) h0[i] = 0.f;
    if (i < NGRU * SLOTP) hslot[i] = 0;
    if (i < NBLK * SLOTP) pkslot[i] = 0;
    if (i < 1088) extra[i] = 0;        // go_h(32) + go_pk(32) + toklines(1024)
}

// ==================== fallback multi-kernel path (R6-proven, 256 thr) ====================
__global__ __launch_bounds__(256) void gru_step_fb(
    const float* __restrict__ h_in, float* __restrict__ h_out,
    const float* __restrict__ Wih, const float* __restrict__ Whh,
    const float* __restrict__ bih, const float* __restrict__ bhh,
    const float* __restrict__ emb,
    const int* __restrict__ enc_tokens, int t, const u64* __restrict__ pk)
{
    __shared__ __align__(16) float hlt[BATCH][HLDS_W];
    __shared__ int tok_s[BATCH];
    __shared__ u64 redk[BATCH][8];
    const int tid = threadIdx.x;

    if (enc_tokens != nullptr) {
        if (tid < BATCH) tok_s[tid] = enc_tokens[tid * SEQ + t];
    } else if (t == 0) {
        if (tid < BATCH) tok_s[tid] = 0;
    } else {
        argmax_finalize(tid, pk, redk, tok_s);
    }
    stage_h(&hlt[0][0], h_in, tid);
    __syncthreads();
    gru_j(blockIdx.x * 4 + (tid >> 6), tid, tok_s, &hlt[0][0], h_out,
          Wih, Whh, bih, bhh, emb);
}

__global__ __launch_bounds__(256) void logits_fb(
    const float* __restrict__ h, const float* __restrict__ outW,
    const float* __restrict__ outb, float* __restrict__ out,
    int t, u64* __restrict__ pk)
{
    __shared__ __align__(16) float hlt[BATCH][HLDS_W];
    const int tid = threadIdx.x;
    stage_h(&hlt[0][0], h, tid);
    __syncthreads();
    logits_core(blockIdx.x, tid, &hlt[0][0], outW, outb, out, t, pk);
}

__global__ __launch_bounds__(256) void copy_fb(const float* __restrict__ src,
                                               float* __restrict__ dst, int n) {
    int i = blockIdx.x * 256 + threadIdx.x;
    if (i < n) dst[i] = src[i];
}

__global__ __launch_bounds__(256) void softmax_kernel(float* __restrict__ out) {
    __shared__ float redm[4];
    __shared__ float reds[4];
    softmax_row(out + (size_t)blockIdx.x * VOCAB, threadIdx.x, redm, reds);
}

extern "C" void kernel_launch(void* const* d_in, const int* in_sizes, int n_in,
                              void* d_out, int out_size, void* d_ws, size_t ws_size,
                              hipStream_t stream) {
    const int*   input    = (const int*)  d_in[0];
    const float* enc_emb  = (const float*)d_in[1];
    const float* enc_Wih  = (const float*)d_in[2];
    const float* enc_Whh  = (const float*)d_in[3];
    const float* enc_bih  = (const float*)d_in[4];
    const float* enc_bhh  = (const float*)d_in[5];
    const float* dec_emb  = (const float*)d_in[6];
    const float* dec_Wih  = (const float*)d_in[7];
    const float* dec_Whh  = (const float*)d_in[8];
    const float* dec_bih  = (const float*)d_in[9];
    const float* dec_bhh  = (const float*)d_in[10];
    const float* out_W    = (const float*)d_in[11];
    const float* out_b    = (const float*)d_in[12];

    float* out = (float*)d_out;
    char*  ws  = (char*)d_ws;

    float* hglob   = (float*)ws;                     // 131072 B
    u64*   pk      = (u64*)(ws + 131072);            // 65536 B
    u32*   hslot   = (u32*)(ws + 196608);            // 16384 B (128 lines)
    u32*   pkslot  = (u32*)(ws + 212992);            // 32768 B (256 lines)
    u32*   extra   = (u32*)(ws + 245760);            // go_h, go_pk, toklines
    u32*   go_h    = extra;                          // 1 line
    u32*   go_pk   = extra + SLOTP;                  // 1 line
    u64*   tokline = (u64*)(extra + 2 * SLOTP);      // 32 lines (16 u64 each)

    init_kernel<<<dim3(64), dim3(256), 0, stream>>>(hglob, hslot, pkslot, extra);

    void* args[] = {
        (void*)&input, (void*)&enc_emb, (void*)&enc_Wih, (void*)&enc_Whh,
        (void*)&enc_bih, (void*)&enc_bhh,
        (void*)&dec_emb, (void*)&dec_Wih, (void*)&dec_Whh, (void*)&dec_bih,
        (void*)&dec_bhh, (void*)&out_W, (void*)&out_b,
        (void*)&out, (void*)&hglob, (void*)&pk,
        (void*)&hslot, (void*)&pkslot, (void*)&go_h, (void*)&go_pk, (void*)&tokline
    };
    hipError_t rc = hipLaunchCooperativeKernel((void*)seq2seq_main,
                                               dim3(NBLK), dim3(NTHR),
                                               args, 0, stream);
    if (rc != hipSuccess) {
        // fallback: multi-kernel path (kernel boundaries provide ordering)
        float* hb[2] = { hglob, hglob + BATCH * HDIM };
        for (int t = 0; t < SEQ; ++t) {
            gru_step_fb<<<dim3(128), dim3(256), 0, stream>>>(
                hb[t & 1], hb[(t + 1) & 1],
                enc_Wih, enc_Whh, enc_bih, enc_bhh, enc_emb, input, t, nullptr);
        }
        for (int t = 0; t < SEQ; ++t) {
            gru_step_fb<<<dim3(128), dim3(256), 0, stream>>>(
                hb[t & 1], hb[(t + 1) & 1],
                dec_Wih, dec_Whh, dec_bih, dec_bhh, dec_emb, nullptr, t, pk);
            logits_fb<<<dim3(NBLK), dim3(256), 0, stream>>>(
                hb[(t + 1) & 1], out_W, out_b, out, t, pk);
        }
        copy_fb<<<dim3((BATCH * HDIM + 255) / 256), dim3(256), 0, stream>>>(
            hglob, out + (size_t)BATCH * SEQ * VOCAB, BATCH * HDIM);
    }

    softmax_kernel<<<dim3(BATCH * SEQ), dim3(256), 0, stream>>>(out);
}

// Round 14
// 9358.150 us; speedup vs baseline: 2.7219x; 1.0866x over previous
//
#include <hip/hip_runtime.h>

#define HDIM 512
#define BATCH 32
#define SEQ 128
#define VOCAB 16384
#define NBLK 256
#define NGRU 128          // GRU blocks: j = blk*4 + wave (R8-proven spread)
#define NTHR 256
#define SLOTP 32          // u32s per 128B flag line
#define HLDS_W 516        // padded LDS row (4-way conflicts only)

typedef unsigned long long u64;
typedef unsigned int u32;
typedef __attribute__((ext_vector_type(2))) unsigned long long u64x2;

// ---------------- MALL agent-relaxed accessors (validated R5/R6/R8) ----------------
static __device__ __forceinline__ u64 aload64(const u64* p) {
    return __hip_atomic_load(p, __ATOMIC_RELAXED, __HIP_MEMORY_SCOPE_AGENT);
}
static __device__ __forceinline__ void astore64(u64* p, u64 v) {
    __hip_atomic_store(p, v, __ATOMIC_RELAXED, __HIP_MEMORY_SCOPE_AGENT);
}
static __device__ __forceinline__ u32 aload32(const u32* p) {
    return __hip_atomic_load(p, __ATOMIC_RELAXED, __HIP_MEMORY_SCOPE_AGENT);
}
static __device__ __forceinline__ void astore32(u32* p, u32 v) {
    __hip_atomic_store(p, v, __ATOMIC_RELAXED, __HIP_MEMORY_SCOPE_AGENT);
}
static __device__ __forceinline__ void astore32f(float* p, float v) {
    __hip_atomic_store((u32*)p, __float_as_uint(v), __ATOMIC_RELAXED,
                       __HIP_MEMORY_SCOPE_AGENT);
}

static __device__ __forceinline__ float4 ld4(const float* p) {
    return *reinterpret_cast<const float4*>(p);
}
static __device__ __forceinline__ float dot4(float4 a, float4 b) {
    return a.x*b.x + a.y*b.y + a.z*b.z + a.w*b.w;
}
static __device__ __forceinline__ u32 ford(float f) {   // monotone float->u32
    u32 b = __float_as_uint(f);
    return b ^ ((b >> 31) ? 0xFFFFFFFFu : 0x80000000u);
}
static __device__ __forceinline__ u64 shfl_xor_u64(u64 x, int m) {
    int lo = __shfl_xor((int)(u32)x, m);
    int hi = __shfl_xor((int)(u32)(x >> 32), m);
    return ((u64)(u32)hi << 32) | (u32)lo;
}

// R14 epoch-embedded argmax key: bits[46..53]=epoch(t+1), [14..45]=ford(s),
// [0..13]=16383-v (tie-break: smaller v wins). Same total order within a
// step as the old (ford<<32)|~v  => identical argmax token.
static __device__ __forceinline__ u64 mkkey(int t, float s, int v) {
    return ((u64)(u32)(t + 1) << 46) | ((u64)ford(s) << 14) | (u32)(16383 - v);
}

// ---- poll nslots per-block flag lines (read-only, first wave only) ----
static __device__ __forceinline__ void pollN(const u32* slots, u32 target,
                                             int tid, int nslots) {
    if (tid < 64) {
        const int per = (nslots + 63) >> 6;
        int it = 0;
        for (;;) {
            bool ok = true;
            for (int k = 0; k < per; ++k) {
                int idx = tid * per + k;
                if (idx < nslots)
                    ok &= (aload32(&slots[idx * SLOTP]) >= target);
            }
            if (__ballot(ok) == ~0ull) break;
            if (it > 64)      __builtin_amdgcn_s_sleep(16);
            else if (it > 8)  __builtin_amdgcn_s_sleep(2);
            ++it;
        }
    }
    __syncthreads();
    asm volatile("" ::: "memory");
}

// ---- stage 64KB h from MALL into LDS: wide sc1 loads (R8-proven) ----
static __device__ __forceinline__ void stage_wide(float* hlf, const float* hsrc, int tid) {
    #pragma unroll
    for (int g = 0; g < 2; ++g) {
        float4 v[8];
        #pragma unroll
        for (int k = 0; k < 8; ++k) {
            int q = (g * 8 + k) * NTHR + tid;            // float4 index
            asm volatile("global_load_dwordx4 %0, %1, off sc1"
                         : "=v"(v[k]) : "v"(hsrc + q * 4));
        }
        asm volatile("s_waitcnt vmcnt(0)" ::: "memory");
        __builtin_amdgcn_sched_barrier(0);
        #pragma unroll
        for (int k = 0; k < 8; ++k) {
            int q = (g * 8 + k) * NTHR + tid;
            int w = q * 4;
            *reinterpret_cast<float4*>(hlf + (w >> 9) * HLDS_W + (w & 511)) = v[k];
        }
    }
}

// ---- stage via relaxed-atomic u64 (fallback kernels only; R6-proven) ----
static __device__ __forceinline__ void stage_h(float* hlf, const float* hglob, int tid) {
    const u64* src = (const u64*)hglob;
    #pragma unroll
    for (int it = 0; it < 32; ++it) {
        int q = it * 256 + tid;
        int w = q * 2;
        u64 v = aload64(src + q);
        *reinterpret_cast<u64*>(hlf + (w >> 9) * HLDS_W + (w & 511)) = v;
    }
}

// ---- GRU for one j: bit-identical arithmetic since round 1 ----
static __device__ __forceinline__ void gru_j(
    int j, int tid, const int* toks, const float* hlf, float* hout,
    const float* __restrict__ Wih, const float* __restrict__ Whh,
    const float* __restrict__ bih, const float* __restrict__ bhh,
    const float* __restrict__ emb)
{
    const int lane = tid & 63;
    const int kh   = lane >> 5;
    const int b    = lane & 31;

    const int tok = toks[b];
    const float* xrow = emb + (size_t)tok * HDIM + kh * 256;
    const float* hrow = hlf + b * HLDS_W + kh * 256;
    const float* wir = Wih + (size_t)(0*HDIM + j) * HDIM + kh * 256;
    const float* wiz = Wih + (size_t)(1*HDIM + j) * HDIM + kh * 256;
    const float* win = Wih + (size_t)(2*HDIM + j) * HDIM + kh * 256;
    const float* whr = Whh + (size_t)(0*HDIM + j) * HDIM + kh * 256;
    const float* whz = Whh + (size_t)(1*HDIM + j) * HDIM + kh * 256;
    const float* whn = Whh + (size_t)(2*HDIM + j) * HDIM + kh * 256;

    float pr = 0.f, pz = 0.f, pxn = 0.f, phn = 0.f;
    #pragma unroll 4
    for (int k4 = 0; k4 < 64; ++k4) {
        float4 x4 = ld4(xrow + k4*4);
        float4 h4 = ld4(hrow + k4*4);
        pr  += dot4(x4, ld4(wir + k4*4)) + dot4(h4, ld4(whr + k4*4));
        pz  += dot4(x4, ld4(wiz + k4*4)) + dot4(h4, ld4(whz + k4*4));
        pxn += dot4(x4, ld4(win + k4*4));
        phn += dot4(h4, ld4(whn + k4*4));
    }
    pr  += __shfl_xor(pr, 32);
    pz  += __shfl_xor(pz, 32);
    pxn += __shfl_xor(pxn, 32);
    phn += __shfl_xor(phn, 32);

    if (kh == 0) {
        float r = 1.f / (1.f + expf(-(pr + bih[j]      + bhh[j])));
        float z = 1.f / (1.f + expf(-(pz + bih[HDIM+j] + bhh[HDIM+j])));
        float n = tanhf(pxn + bih[2*HDIM+j] + r * (phn + bhh[2*HDIM+j]));
        float hprev = hlf[b * HLDS_W + j];
        astore32f(hout + b * HDIM + j, (1.f - z) * n + z * hprev);
    }
}

// ---- logits core: exact R8 float arithmetic; only the key format changed ----
static __device__ __forceinline__ void logits_core(
    int blk, int tid, const float* hlf,
    const float* __restrict__ outW, const float* __restrict__ outb,
    float* __restrict__ out, int t, u64* pk)
{
    const int vloc = tid & 63;
    const int bq   = tid >> 6;
    const int v    = blk * 64 + vloc;
    const float* wrow = outW + (size_t)v * HDIM;

    float acc[4][8];
    #pragma unroll
    for (int q = 0; q < 4; ++q)
        #pragma unroll
        for (int i = 0; i < 8; ++i) acc[q][i] = 0.f;

    #pragma unroll
    for (int q = 0; q < 4; ++q) {
        for (int k4 = 0; k4 < 32; ++k4) {
            float4 w4 = ld4(wrow + q*128 + k4*4);
            #pragma unroll
            for (int i = 0; i < 8; ++i) {
                float4 h4 = ld4(hlf + (bq*8 + i) * HLDS_W + q*128 + k4*4);
                acc[q][i] += dot4(w4, h4);
            }
        }
    }
    const float vbias = outb[v];
    #pragma unroll
    for (int i = 0; i < 8; ++i) {
        const int b = bq*8 + i;
        float s = ((acc[0][i] + acc[1][i]) + acc[2][i]) + acc[3][i] + vbias;
        __builtin_nontemporal_store(s, &out[(size_t)b*(SEQ*VOCAB) + (size_t)t*VOCAB + v]);
        u64 key = mkkey(t, s, v);
        #pragma unroll
        for (int d = 1; d < 64; d <<= 1) {
            u64 o = shfl_xor_u64(key, d);
            if (o > key) key = o;
        }
        if (vloc == 0) astore64(pk + b * NBLK + blk, key);
    }
}

// ---- argmax finalize (fallback path only; new key format) ----
static __device__ __forceinline__ void argmax_finalize(
    int tid, const u64* pk, u64 (*redk)[8], int* tok_s)
{
    const int fb = tid >> 3, kc = tid & 7;
    const u64* p = pk + fb * NBLK;
    u64 best = aload64(p + kc);
    #pragma unroll 4
    for (int k = 1; k < 32; ++k) {
        u64 x = aload64(p + kc + k * 8);
        if (x > best) best = x;
    }
    redk[fb][kc] = best;
    __syncthreads();
    if (tid < BATCH) {
        u64 bb = redk[tid][0];
        #pragma unroll
        for (int c = 1; c < 8; ++c) { u64 x = redk[tid][c]; if (x > bb) bb = x; }
        tok_s[tid] = 16383 - (int)(bb & 0x3FFF);
    }
}

// ---- log_softmax row (256 threads) ----
static __device__ __forceinline__ void softmax_row(float* p, int tid,
                                                   float* redm, float* reds) {
    float4 vals[16];
    float m = -3.4e38f;
    #pragma unroll
    for (int i = 0; i < 16; ++i) {
        vals[i] = ld4(p + (i * 256 + tid) * 4);
        m = fmaxf(m, fmaxf(fmaxf(vals[i].x, vals[i].y), fmaxf(vals[i].z, vals[i].w)));
    }
    #pragma unroll
    for (int d = 1; d < 64; d <<= 1) m = fmaxf(m, __shfl_xor(m, d));
    if ((tid & 63) == 0) redm[tid >> 6] = m;
    __syncthreads();
    m = fmaxf(fmaxf(redm[0], redm[1]), fmaxf(redm[2], redm[3]));
    float s = 0.f;
    #pragma unroll
    for (int i = 0; i < 16; ++i) {
        s += expf(vals[i].x - m) + expf(vals[i].y - m)
           + expf(vals[i].z - m) + expf(vals[i].w - m);
    }
    #pragma unroll
    for (int d = 1; d < 64; d <<= 1) s += __shfl_xor(s, d);
    if ((tid & 63) == 0) reds[tid >> 6] = s;
    __syncthreads();
    s = reds[0] + reds[1] + reds[2] + reds[3];
    const float lg = m + logf(s);
    #pragma unroll
    for (int i = 0; i < 16; ++i) {
        float4 r;
        r.x = vals[i].x - lg; r.y = vals[i].y - lg;
        r.z = vals[i].z - lg; r.w = vals[i].w - lg;
        *reinterpret_cast<float4*>(p + (i * 256 + tid) * 4) = r;
    }
    __syncthreads();
}

// ==================== persistent cooperative kernel ====================
__global__ __launch_bounds__(NTHR, 1) void seq2seq_main(
    const int* __restrict__ input,
    const float* __restrict__ enc_emb, const float* __restrict__ enc_Wih,
    const float* __restrict__ enc_Whh, const float* __restrict__ enc_bih,
    const float* __restrict__ enc_bhh,
    const float* __restrict__ dec_emb, const float* __restrict__ dec_Wih,
    const float* __restrict__ dec_Whh, const float* __restrict__ dec_bih,
    const float* __restrict__ dec_bhh,
    const float* __restrict__ out_W, const float* __restrict__ out_b,
    float* __restrict__ out, float* hglob, u64* pk,
    u32* hslot, u64* tokline)
{
    __shared__ __align__(16) float hl[BATCH][HLDS_W];   // 66048 B
    __shared__ int tok_s[BATCH];

    const int tid = threadIdx.x;
    const int blk = blockIdx.x;
    float* hlf = &hl[0][0];

    // hlf = h(0) = 0 (encoder step 0 input)
    for (int i = tid; i < BATCH * HLDS_W; i += NTHR) hlf[i] = 0.f;
    __syncthreads();

    const int w = tid >> 6;          // wave 0..3

    // ---------------- encoder: 128 steps (blocks 0..127 only) ----------------
    if (blk < NGRU) {
        for (int t = 0; t < SEQ; ++t) {
            float* hgo = hglob + ((t + 1) & 1) * (BATCH * HDIM);
            if (tid < BATCH) tok_s[tid] = input[tid * SEQ + t];
            __syncthreads();
            gru_j(blk * 4 + w, tid, tok_s, hlf, hgo,
                  enc_Wih, enc_Whh, enc_bih, enc_bhh, enc_emb);
            __syncthreads();                          // drains all waves' stores
            if (tid == 0) astore32(&hslot[blk * SLOTP], (u32)(t + 1));
            pollN(hslot, (u32)(t + 1), tid, NGRU);    // h(t+1) @ MALL
            stage_wide(hlf, hgo, tid);                // hlf <- h(t+1)
            __syncthreads();
        }
    }

    // ---------------- decoder: 128 steps ----------------
    for (int t = 0; t < SEQ; ++t) {
        float* hgo = hglob + ((t + 1) & 1) * (BATCH * HDIM);

        if (blk < NGRU) {
            if (t == 0) {
                if (tid < BATCH) tok_s[tid] = 0;      // SOS
                __syncthreads();
            } else {
                // ---- R14 gather: poll pk VALUES (epoch-embedded) directly ----
                if (blk < BATCH) {                    // gatherer for row b = blk
                    if (tid < 64) {
                        const u64* prow = pk + (size_t)blk * NBLK + tid * 4;
                        u64x2 a, b2;
                        const u32 ep = (u32)t;        // keys from logits(t-1)
                        int it = 0;
                        for (;;) {
                            asm volatile("global_load_dwordx4 %0, %1, off sc1"
                                         : "=v"(a) : "v"(prow));
                            asm volatile("global_load_dwordx4 %0, %1, off sc1"
                                         : "=v"(b2) : "v"(prow + 2));
                            asm volatile("s_waitcnt vmcnt(0)" ::: "memory");
                            bool ok = ((u32)(a.x  >> 46) == ep) &&
                                      ((u32)(a.y  >> 46) == ep) &&
                                      ((u32)(b2.x >> 46) == ep) &&
                                      ((u32)(b2.y >> 46) == ep);
                            if (__ballot(ok) == ~0ull) break;
                            if (it > 64)      __builtin_amdgcn_s_sleep(16);
                            else if (it > 8)  __builtin_amdgcn_s_sleep(2);
                            ++it;
                        }
                        u64 best = a.x;
                        if (a.y  > best) best = a.y;
                        if (b2.x > best) best = b2.x;
                        if (b2.y > best) best = b2.y;
                        #pragma unroll
                        for (int d = 1; d < 64; d <<= 1) {
                            u64 o = shfl_xor_u64(best, d);
                            if (o > best) best = o;
                        }
                        if (tid == 0)
                            astore64(&tokline[blk * 16],
                                     ((u64)(u32)t << 32) |
                                     (u32)(16383 - (u32)(best & 0x3FFF)));
                    }
                }
                // all GRU blocks: poll the 32 token lines (epoch t)
                if (tid < 64) {
                    u64 tv = 0; int it = 0;
                    for (;;) {
                        bool ok = true;
                        if (tid < 32) {
                            tv = aload64(&tokline[tid * 16]);
                            ok = ((u32)(tv >> 32) >= (u32)t);
                        }
                        if (__ballot(ok) == ~0ull) break;
                        if (it > 64)      __builtin_amdgcn_s_sleep(16);
                        else if (it > 8)  __builtin_amdgcn_s_sleep(2);
                        ++it;
                    }
                    if (tid < 32) tok_s[tid] = (int)(u32)tv;
                }
                __syncthreads();
            }
            // hlf holds h(t); compute h(t+1)
            gru_j(blk * 4 + w, tid, tok_s, hlf, hgo,
                  dec_Wih, dec_Whh, dec_bih, dec_bhh, dec_emb);
            __syncthreads();
            if (tid == 0) astore32(&hslot[blk * SLOTP], (u32)(SEQ + t + 1));
        }

        pollN(hslot, (u32)(SEQ + t + 1), tid, NGRU);  // h(t+1) @ MALL
        stage_wide(hlf, hgo, tid);                    // hlf <- h(t+1)
        __syncthreads();
        logits_core(blk, tid, hlf, out_W, out_b, out, t, pk);
        // no flag, no barrier: pk visibility is polled on the values themselves;
        // next iteration's pollN provides the intra-block barrier.
    }

    // ---- final decoder hidden: hlf holds h(dec,128) on every block ----
    if (blk < 16) {
        const int idx = blk * 1024 + tid * 4;
        const int b = idx >> 9, j = idx & 511;
        *reinterpret_cast<float4*>(out + (size_t)BATCH * SEQ * VOCAB + idx) =
            *reinterpret_cast<const float4*>(&hl[b][j]);
    }
}

// ---- init: zero h0, hslot, toklines, pk (ws not re-poisoned between replays;
//      pk MUST be cleared so epoch-equality polls can't see stale epochs) ----
__global__ __launch_bounds__(256) void init_kernel(float* __restrict__ h0,
                                                   u32* __restrict__ hslot,
                                                   u32* __restrict__ pk32,
                                                   u32* __restrict__ tokl32) {
    int i = blockIdx.x * 256 + threadIdx.x;
    if (i < BATCH * HDIM) h0[i] = 0.f;
    if (i < NGRU * SLOTP) hslot[i] = 0;
    if (i < 16384) pk32[i] = 0;        // 8192 u64
    if (i < 1024) tokl32[i] = 0;       // 32 lines x 16 u64
}

// ==================== fallback multi-kernel path (R6-proven, 256 thr) ====================
__global__ __launch_bounds__(256) void gru_step_fb(
    const float* __restrict__ h_in, float* __restrict__ h_out,
    const float* __restrict__ Wih, const float* __restrict__ Whh,
    const float* __restrict__ bih, const float* __restrict__ bhh,
    const float* __restrict__ emb,
    const int* __restrict__ enc_tokens, int t, const u64* __restrict__ pk)
{
    __shared__ __align__(16) float hlt[BATCH][HLDS_W];
    __shared__ int tok_s[BATCH];
    __shared__ u64 redk[BATCH][8];
    const int tid = threadIdx.x;

    if (enc_tokens != nullptr) {
        if (tid < BATCH) tok_s[tid] = enc_tokens[tid * SEQ + t];
    } else if (t == 0) {
        if (tid < BATCH) tok_s[tid] = 0;
    } else {
        argmax_finalize(tid, pk, redk, tok_s);
    }
    stage_h(&hlt[0][0], h_in, tid);
    __syncthreads();
    gru_j(blockIdx.x * 4 + (tid >> 6), tid, tok_s, &hlt[0][0], h_out,
          Wih, Whh, bih, bhh, emb);
}

__global__ __launch_bounds__(256) void logits_fb(
    const float* __restrict__ h, const float* __restrict__ outW,
    const float* __restrict__ outb, float* __restrict__ out,
    int t, u64* __restrict__ pk)
{
    __shared__ __align__(16) float hlt[BATCH][HLDS_W];
    const int tid = threadIdx.x;
    stage_h(&hlt[0][0], h, tid);
    __syncthreads();
    logits_core(blockIdx.x, tid, &hlt[0][0], outW, outb, out, t, pk);
}

__global__ __launch_bounds__(256) void copy_fb(const float* __restrict__ src,
                                               float* __restrict__ dst, int n) {
    int i = blockIdx.x * 256 + threadIdx.x;
    if (i < n) dst[i] = src[i];
}

__global__ __launch_bounds__(256) void softmax_kernel(float* __restrict__ out) {
    __shared__ float redm[4];
    __shared__ float reds[4];
    softmax_row(out + (size_t)blockIdx.x * VOCAB, threadIdx.x, redm, reds);
}

extern "C" void kernel_launch(void* const* d_in, const int* in_sizes, int n_in,
                              void* d_out, int out_size, void* d_ws, size_t ws_size,
                              hipStream_t stream) {
    const int*   input    = (const int*)  d_in[0];
    const float* enc_emb  = (const float*)d_in[1];
    const float* enc_Wih  = (const float*)d_in[2];
    const float* enc_Whh  = (const float*)d_in[3];
    const float* enc_bih  = (const float*)d_in[4];
    const float* enc_bhh  = (const float*)d_in[5];
    const float* dec_emb  = (const float*)d_in[6];
    const float* dec_Wih  = (const float*)d_in[7];
    const float* dec_Whh  = (const float*)d_in[8];
    const float* dec_bih  = (const float*)d_in[9];
    const float* dec_bhh  = (const float*)d_in[10];
    const float* out_W    = (const float*)d_in[11];
    const float* out_b    = (const float*)d_in[12];

    float* out = (float*)d_out;
    char*  ws  = (char*)d_ws;

    float* hglob   = (float*)ws;                     // 131072 B
    u64*   pk      = (u64*)(ws + 131072);            // 65536 B
    u32*   hslot   = (u32*)(ws + 196608);            // 16384 B (128 lines)
    u64*   tokline = (u64*)(ws + 212992);            // 4096 B (32 lines)

    init_kernel<<<dim3(64), dim3(256), 0, stream>>>(hglob, hslot,
                                                    (u32*)pk, (u32*)tokline);

    void* args[] = {
        (void*)&input, (void*)&enc_emb, (void*)&enc_Wih, (void*)&enc_Whh,
        (void*)&enc_bih, (void*)&enc_bhh,
        (void*)&dec_emb, (void*)&dec_Wih, (void*)&dec_Whh, (void*)&dec_bih,
        (void*)&dec_bhh, (void*)&out_W, (void*)&out_b,
        (void*)&out, (void*)&hglob, (void*)&pk,
        (void*)&hslot, (void*)&tokline
    };
    hipError_t rc = hipLaunchCooperativeKernel((void*)seq2seq_main,
                                               dim3(NBLK), dim3(NTHR),
                                               args, 0, stream);
    if (rc != hipSuccess) {
        // fallback: multi-kernel path (kernel boundaries provide ordering)
        float* hb[2] = { hglob, hglob + BATCH * HDIM };
        for (int t = 0; t < SEQ; ++t) {
            gru_step_fb<<<dim3(128), dim3(256), 0, stream>>>(
                hb[t & 1], hb[(t + 1) & 1],
                enc_Wih, enc_Whh, enc_bih, enc_bhh, enc_emb, input, t, nullptr);
        }
        for (int t = 0; t < SEQ; ++t) {
            gru_step_fb<<<dim3(128), dim3(256), 0, stream>>>(
                hb[t & 1], hb[(t + 1) & 1],
                dec_Wih, dec_Whh, dec_bih, dec_bhh, dec_emb, nullptr, t, pk);
            logits_fb<<<dim3(NBLK), dim3(256), 0, stream>>>(
                hb[(t + 1) & 1], out_W, out_b, out, t, pk);
        }
        copy_fb<<<dim3((BATCH * HDIM + 255) / 256), dim3(256), 0, stream>>>(
            hglob, out + (size_t)BATCH * SEQ * VOCAB, BATCH * HDIM);
    }

    softmax_kernel<<<dim3(BATCH * SEQ), dim3(256), 0, stream>>>(out);
}

// Round 17
// 9267.338 us; speedup vs baseline: 2.7486x; 1.0098x over previous
//
#include <hip/hip_runtime.h>

#define HDIM 512
#define BATCH 32
#define SEQ 128
#define VOCAB 16384
#define NBLK 256
#define NGRU 128          // GRU blocks: j = blk*4 + wave (R8-proven spread)
#define NTHR 256
#define SLOTP 32          // u32s per 128B flag line
#define HLDS_W 516        // padded LDS row (4-way conflicts only)

typedef unsigned long long u64;
typedef unsigned int u32;
typedef __attribute__((ext_vector_type(2))) unsigned long long u64x2;

// ---------------- MALL agent-relaxed accessors (validated R5/R6/R8/R14) ----------------
static __device__ __forceinline__ u64 aload64(const u64* p) {
    return __hip_atomic_load(p, __ATOMIC_RELAXED, __HIP_MEMORY_SCOPE_AGENT);
}
static __device__ __forceinline__ void astore64(u64* p, u64 v) {
    __hip_atomic_store(p, v, __ATOMIC_RELAXED, __HIP_MEMORY_SCOPE_AGENT);
}
static __device__ __forceinline__ u32 aload32(const u32* p) {
    return __hip_atomic_load(p, __ATOMIC_RELAXED, __HIP_MEMORY_SCOPE_AGENT);
}
static __device__ __forceinline__ void astore32(u32* p, u32 v) {
    __hip_atomic_store(p, v, __ATOMIC_RELAXED, __HIP_MEMORY_SCOPE_AGENT);
}
static __device__ __forceinline__ void astore32f(float* p, float v) {
    __hip_atomic_store((u32*)p, __float_as_uint(v), __ATOMIC_RELAXED,
                       __HIP_MEMORY_SCOPE_AGENT);
}

static __device__ __forceinline__ float4 ld4(const float* p) {
    return *reinterpret_cast<const float4*>(p);
}
static __device__ __forceinline__ float dot4(float4 a, float4 b) {
    return a.x*b.x + a.y*b.y + a.z*b.z + a.w*b.w;
}
static __device__ __forceinline__ u32 ford(float f) {   // monotone float->u32
    u32 b = __float_as_uint(f);
    return b ^ ((b >> 31) ? 0xFFFFFFFFu : 0x80000000u);
}
static __device__ __forceinline__ u64 shfl_xor_u64(u64 x, int m) {
    int lo = __shfl_xor((int)(u32)x, m);
    int hi = __shfl_xor((int)(u32)(x >> 32), m);
    return ((u64)(u32)hi << 32) | (u32)lo;
}

// R14 epoch-embedded argmax key: bits[46..53]=epoch(t+1), [14..45]=ford(s),
// [0..13]=16383-v (tie-break: smaller v wins). Same total order within a
// step as (ford<<32)|~v  => identical argmax token.
static __device__ __forceinline__ u64 mkkey(int t, float s, int v) {
    return ((u64)(u32)(t + 1) << 46) | ((u64)ford(s) << 14) | (u32)(16383 - v);
}

// ---- poll nslots per-block flag lines (read-only, first wave only) ----
static __device__ __forceinline__ void pollN(const u32* slots, u32 target,
                                             int tid, int nslots) {
    if (tid < 64) {
        const int per = (nslots + 63) >> 6;
        int it = 0;
        for (;;) {
            bool ok = true;
            for (int k = 0; k < per; ++k) {
                int idx = tid * per + k;
                if (idx < nslots)
                    ok &= (aload32(&slots[idx * SLOTP]) >= target);
            }
            if (__ballot(ok) == ~0ull) break;
            if (it > 64)      __builtin_amdgcn_s_sleep(16);
            else if (it > 8)  __builtin_amdgcn_s_sleep(2);
            ++it;
        }
    }
    __syncthreads();
    asm volatile("" ::: "memory");
}

// ---- stage 64KB h from MALL into LDS: wide sc1 loads (R8-proven) ----
static __device__ __forceinline__ void stage_wide(float* hlf, const float* hsrc, int tid) {
    #pragma unroll
    for (int g = 0; g < 2; ++g) {
        float4 v[8];
        #pragma unroll
        for (int k = 0; k < 8; ++k) {
            int q = (g * 8 + k) * NTHR + tid;            // float4 index
            asm volatile("global_load_dwordx4 %0, %1, off sc1"
                         : "=v"(v[k]) : "v"(hsrc + q * 4));
        }
        asm volatile("s_waitcnt vmcnt(0)" ::: "memory");
        __builtin_amdgcn_sched_barrier(0);
        #pragma unroll
        for (int k = 0; k < 8; ++k) {
            int q = (g * 8 + k) * NTHR + tid;
            int w = q * 4;
            *reinterpret_cast<float4*>(hlf + (w >> 9) * HLDS_W + (w & 511)) = v[k];
        }
    }
}

// ---- stage via relaxed-atomic u64 (fallback kernels only; R6-proven) ----
static __device__ __forceinline__ void stage_h(float* hlf, const float* hglob, int tid) {
    const u64* src = (const u64*)hglob;
    #pragma unroll
    for (int it = 0; it < 32; ++it) {
        int q = it * 256 + tid;
        int w = q * 2;
        u64 v = aload64(src + q);
        *reinterpret_cast<u64*>(hlf + (w >> 9) * HLDS_W + (w & 511)) = v;
    }
}

// ---- GRU for one j: bit-identical arithmetic since round 1 ----
static __device__ __forceinline__ void gru_j(
    int j, int tid, const int* toks, const float* hlf, float* hout,
    const float* __restrict__ Wih, const float* __restrict__ Whh,
    const float* __restrict__ bih, const float* __restrict__ bhh,
    const float* __restrict__ emb)
{
    const int lane = tid & 63;
    const int kh   = lane >> 5;
    const int b    = lane & 31;

    const int tok = toks[b];
    const float* xrow = emb + (size_t)tok * HDIM + kh * 256;
    const float* hrow = hlf + b * HLDS_W + kh * 256;
    const float* wir = Wih + (size_t)(0*HDIM + j) * HDIM + kh * 256;
    const float* wiz = Wih + (size_t)(1*HDIM + j) * HDIM + kh * 256;
    const float* win = Wih + (size_t)(2*HDIM + j) * HDIM + kh * 256;
    const float* whr = Whh + (size_t)(0*HDIM + j) * HDIM + kh * 256;
    const float* whz = Whh + (size_t)(1*HDIM + j) * HDIM + kh * 256;
    const float* whn = Whh + (size_t)(2*HDIM + j) * HDIM + kh * 256;

    float pr = 0.f, pz = 0.f, pxn = 0.f, phn = 0.f;
    #pragma unroll 4
    for (int k4 = 0; k4 < 64; ++k4) {
        float4 x4 = ld4(xrow + k4*4);
        float4 h4 = ld4(hrow + k4*4);
        pr  += dot4(x4, ld4(wir + k4*4)) + dot4(h4, ld4(whr + k4*4));
        pz  += dot4(x4, ld4(wiz + k4*4)) + dot4(h4, ld4(whz + k4*4));
        pxn += dot4(x4, ld4(win + k4*4));
        phn += dot4(h4, ld4(whn + k4*4));
    }
    pr  += __shfl_xor(pr, 32);
    pz  += __shfl_xor(pz, 32);
    pxn += __shfl_xor(pxn, 32);
    phn += __shfl_xor(phn, 32);

    if (kh == 0) {
        float r = 1.f / (1.f + expf(-(pr + bih[j]      + bhh[j])));
        float z = 1.f / (1.f + expf(-(pz + bih[HDIM+j] + bhh[HDIM+j])));
        float n = tanhf(pxn + bih[2*HDIM+j] + r * (phn + bhh[2*HDIM+j]));
        float hprev = hlf[b * HLDS_W + j];
        astore32f(hout + b * HDIM + j, (1.f - z) * n + z * hprev);
    }
}

// ---- logits core: exact R8 float arithmetic; R14 epoch-embedded keys ----
static __device__ __forceinline__ void logits_core(
    int blk, int tid, const float* hlf,
    const float* __restrict__ outW, const float* __restrict__ outb,
    float* __restrict__ out, int t, u64* pk)
{
    const int vloc = tid & 63;
    const int bq   = tid >> 6;
    const int v    = blk * 64 + vloc;
    const float* wrow = outW + (size_t)v * HDIM;

    float acc[4][8];
    #pragma unroll
    for (int q = 0; q < 4; ++q)
        #pragma unroll
        for (int i = 0; i < 8; ++i) acc[q][i] = 0.f;

    #pragma unroll
    for (int q = 0; q < 4; ++q) {
        for (int k4 = 0; k4 < 32; ++k4) {
            float4 w4 = ld4(wrow + q*128 + k4*4);
            #pragma unroll
            for (int i = 0; i < 8; ++i) {
                float4 h4 = ld4(hlf + (bq*8 + i) * HLDS_W + q*128 + k4*4);
                acc[q][i] += dot4(w4, h4);
            }
        }
    }
    const float vbias = outb[v];
    #pragma unroll
    for (int i = 0; i < 8; ++i) {
        const int b = bq*8 + i;
        float s = ((acc[0][i] + acc[1][i]) + acc[2][i]) + acc[3][i] + vbias;
        __builtin_nontemporal_store(s, &out[(size_t)b*(SEQ*VOCAB) + (size_t)t*VOCAB + v]);
        u64 key = mkkey(t, s, v);
        #pragma unroll
        for (int d = 1; d < 64; d <<= 1) {
            u64 o = shfl_xor_u64(key, d);
            if (o > key) key = o;
        }
        if (vloc == 0) astore64(pk + b * NBLK + blk, key);
    }
}

// ---- argmax finalize (fallback path only; R14 key format) ----
static __device__ __forceinline__ void argmax_finalize(
    int tid, const u64* pk, u64 (*redk)[8], int* tok_s)
{
    const int fb = tid >> 3, kc = tid & 7;
    const u64* p = pk + fb * NBLK;
    u64 best = aload64(p + kc);
    #pragma unroll 4
    for (int k = 1; k < 32; ++k) {
        u64 x = aload64(p + kc + k * 8);
        if (x > best) best = x;
    }
    redk[fb][kc] = best;
    __syncthreads();
    if (tid < BATCH) {
        u64 bb = redk[tid][0];
        #pragma unroll
        for (int c = 1; c < 8; ++c) { u64 x = redk[tid][c]; if (x > bb) bb = x; }
        tok_s[tid] = 16383 - (int)(bb & 0x3FFF);
    }
}

// ---- log_softmax row (256 threads) ----
static __device__ __forceinline__ void softmax_row(float* p, int tid,
                                                   float* redm, float* reds) {
    float4 vals[16];
    float m = -3.4e38f;
    #pragma unroll
    for (int i = 0; i < 16; ++i) {
        vals[i] = ld4(p + (i * 256 + tid) * 4);
        m = fmaxf(m, fmaxf(fmaxf(vals[i].x, vals[i].y), fmaxf(vals[i].z, vals[i].w)));
    }
    #pragma unroll
    for (int d = 1; d < 64; d <<= 1) m = fmaxf(m, __shfl_xor(m, d));
    if ((tid & 63) == 0) redm[tid >> 6] = m;
    __syncthreads();
    m = fmaxf(fmaxf(redm[0], redm[1]), fmaxf(redm[2], redm[3]));
    float s = 0.f;
    #pragma unroll
    for (int i = 0; i < 16; ++i) {
        s += expf(vals[i].x - m) + expf(vals[i].y - m)
           + expf(vals[i].z - m) + expf(vals[i].w - m);
    }
    #pragma unroll
    for (int d = 1; d < 64; d <<= 1) s += __shfl_xor(s, d);
    if ((tid & 63) == 0) reds[tid >> 6] = s;
    __syncthreads();
    s = reds[0] + reds[1] + reds[2] + reds[3];
    const float lg = m + logf(s);
    #pragma unroll
    for (int i = 0; i < 16; ++i) {
        float4 r;
        r.x = vals[i].x - lg; r.y = vals[i].y - lg;
        r.z = vals[i].z - lg; r.w = vals[i].w - lg;
        *reinterpret_cast<float4*>(p + (i * 256 + tid) * 4) = r;
    }
    __syncthreads();
}

// ==================== persistent cooperative kernel ====================
__global__ __launch_bounds__(NTHR, 1) void seq2seq_main(
    const int* __restrict__ input,
    const float* __restrict__ enc_emb, const float* __restrict__ enc_Wih,
    const float* __restrict__ enc_Whh, const float* __restrict__ enc_bih,
    const float* __restrict__ enc_bhh,
    const float* __restrict__ dec_emb, const float* __restrict__ dec_Wih,
    const float* __restrict__ dec_Whh, const float* __restrict__ dec_bih,
    const float* __restrict__ dec_bhh,
    const float* __restrict__ out_W, const float* __restrict__ out_b,
    float* __restrict__ out, float* hglob, u64* pk,
    u32* hslot, u64* tokline)
{
    __shared__ __align__(16) float hl[BATCH][HLDS_W];   // 66048 B
    __shared__ int tok_s[BATCH];

    const int tid = threadIdx.x;
    const int blk = blockIdx.x;
    float* hlf = &hl[0][0];

    // hlf = h(0) = 0 (encoder step 0 input)
    for (int i = tid; i < BATCH * HLDS_W; i += NTHR) hlf[i] = 0.f;
    __syncthreads();

    const int w = tid >> 6;          // wave 0..3

    // ---------------- encoder: 128 steps (blocks 0..127 only) ----------------
    if (blk < NGRU) {
        for (int t = 0; t < SEQ; ++t) {
            float* hgo = hglob + ((t + 1) & 1) * (BATCH * HDIM);
            if (tid < BATCH) tok_s[tid] = input[tid * SEQ + t];
            __syncthreads();
            gru_j(blk * 4 + w, tid, tok_s, hlf, hgo,
                  enc_Wih, enc_Whh, enc_bih, enc_bhh, enc_emb);
            __syncthreads();                          // drains all waves' stores
            if (tid == 0) astore32(&hslot[blk * SLOTP], (u32)(t + 1));
            pollN(hslot, (u32)(t + 1), tid, NGRU);    // h(t+1) @ MALL
            stage_wide(hlf, hgo, tid);                // hlf <- h(t+1)
            __syncthreads();
        }
    }

    // ---------------- decoder: 128 steps ----------------
    for (int t = 0; t < SEQ; ++t) {
        float* hgo = hglob + ((t + 1) & 1) * (BATCH * HDIM);

        if (blk < NGRU) {
            if (t == 0) {
                if (tid < BATCH) tok_s[tid] = 0;      // SOS
                __syncthreads();
            } else {
                // ---- R14 gather: poll pk VALUES (epoch-embedded) directly ----
                if (blk < BATCH) {                    // gatherer for row b = blk
                    if (tid < 64) {
                        const u64* prow = pk + (size_t)blk * NBLK + tid * 4;
                        u64x2 a, b2;
                        const u32 ep = (u32)t;        // keys from logits(t-1)
                        int it = 0;
                        for (;;) {
                            asm volatile("global_load_dwordx4 %0, %1, off sc1"
                                         : "=v"(a) : "v"(prow));
                            asm volatile("global_load_dwordx4 %0, %1, off sc1"
                                         : "=v"(b2) : "v"(prow + 2));
                            asm volatile("s_waitcnt vmcnt(0)" ::: "memory");
                            bool ok = ((u32)(a.x  >> 46) == ep) &&
                                      ((u32)(a.y  >> 46) == ep) &&
                                      ((u32)(b2.x >> 46) == ep) &&
                                      ((u32)(b2.y >> 46) == ep);
                            if (__ballot(ok) == ~0ull) break;
                            if (it > 64)      __builtin_amdgcn_s_sleep(16);
                            else if (it > 8)  __builtin_amdgcn_s_sleep(2);
                            ++it;
                        }
                        u64 best = a.x;
                        if (a.y  > best) best = a.y;
                        if (b2.x > best) best = b2.x;
                        if (b2.y > best) best = b2.y;
                        #pragma unroll
                        for (int d = 1; d < 64; d <<= 1) {
                            u64 o = shfl_xor_u64(best, d);
                            if (o > best) best = o;
                        }
                        if (tid == 0)
                            astore64(&tokline[blk * 16],
                                     ((u64)(u32)t << 32) |
                                     (u32)(16383 - (u32)(best & 0x3FFF)));
                    }
                }
                // all GRU blocks: poll the 32 token lines (epoch t)
                if (tid < 64) {
                    u64 tv = 0; int it = 0;
                    for (;;) {
                        bool ok = true;
                        if (tid < 32) {
                            tv = aload64(&tokline[tid * 16]);
                            ok = ((u32)(tv >> 32) >= (u32)t);
                        }
                        if (__ballot(ok) == ~0ull) break;
                        if (it > 64)      __builtin_amdgcn_s_sleep(16);
                        else if (it > 8)  __builtin_amdgcn_s_sleep(2);
                        ++it;
                    }
                    if (tid < 32) tok_s[tid] = (int)(u32)tv;
                }
                __syncthreads();
            }
            // hlf holds h(t); compute h(t+1)
            gru_j(blk * 4 + w, tid, tok_s, hlf, hgo,
                  dec_Wih, dec_Whh, dec_bih, dec_bhh, dec_emb);
            __syncthreads();
            if (tid == 0) astore32(&hslot[blk * SLOTP], (u32)(SEQ + t + 1));
        }

        pollN(hslot, (u32)(SEQ + t + 1), tid, NGRU);  // h(t+1) @ MALL
        stage_wide(hlf, hgo, tid);                    // hlf <- h(t+1)
        __syncthreads();
        logits_core(blk, tid, hlf, out_W, out_b, out, t, pk);
        // no flag, no barrier: pk visibility is polled on the values themselves;
        // next iteration's pollN provides the intra-block barrier.
    }

    // ---- final decoder hidden: hlf holds h(dec,128) on every block ----
    if (blk < 16) {
        const int idx = blk * 1024 + tid * 4;
        const int b = idx >> 9, j = idx & 511;
        *reinterpret_cast<float4*>(out + (size_t)BATCH * SEQ * VOCAB + idx) =
            *reinterpret_cast<const float4*>(&hl[b][j]);
    }
}

// ---- init: zero h0, hslot, toklines, pk (ws not re-poisoned between replays;
//      pk MUST be cleared so epoch-equality polls can't see stale epochs) ----
__global__ __launch_bounds__(256) void init_kernel(float* __restrict__ h0,
                                                   u32* __restrict__ hslot,
                                                   u32* __restrict__ pk32,
                                                   u32* __restrict__ tokl32) {
    int i = blockIdx.x * 256 + threadIdx.x;
    if (i < BATCH * HDIM) h0[i] = 0.f;
    if (i < NGRU * SLOTP) hslot[i] = 0;
    if (i < 16384) pk32[i] = 0;        // 8192 u64
    if (i < 1024) tokl32[i] = 0;       // 32 lines x 16 u64
}

// ==================== fallback multi-kernel path (R6-proven, 256 thr) ====================
__global__ __launch_bounds__(256) void gru_step_fb(
    const float* __restrict__ h_in, float* __restrict__ h_out,
    const float* __restrict__ Wih, const float* __restrict__ Whh,
    const float* __restrict__ bih, const float* __restrict__ bhh,
    const float* __restrict__ emb,
    const int* __restrict__ enc_tokens, int t, const u64* __restrict__ pk)
{
    __shared__ __align__(16) float hlt[BATCH][HLDS_W];
    __shared__ int tok_s[BATCH];
    __shared__ u64 redk[BATCH][8];
    const int tid = threadIdx.x;

    if (enc_tokens != nullptr) {
        if (tid < BATCH) tok_s[tid] = enc_tokens[tid * SEQ + t];
    } else if (t == 0) {
        if (tid < BATCH) tok_s[tid] = 0;
    } else {
        argmax_finalize(tid, pk, redk, tok_s);
    }
    stage_h(&hlt[0][0], h_in, tid);
    __syncthreads();
    gru_j(blockIdx.x * 4 + (tid >> 6), tid, tok_s, &hlt[0][0], h_out,
          Wih, Whh, bih, bhh, emb);
}

__global__ __launch_bounds__(256) void logits_fb(
    const float* __restrict__ h, const float* __restrict__ outW,
    const float* __restrict__ outb, float* __restrict__ out,
    int t, u64* __restrict__ pk)
{
    __shared__ __align__(16) float hlt[BATCH][HLDS_W];
    const int tid = threadIdx.x;
    stage_h(&hlt[0][0], h, tid);
    __syncthreads();
    logits_core(blockIdx.x, tid, &hlt[0][0], outW, outb, out, t, pk);
}

__global__ __launch_bounds__(256) void copy_fb(const float* __restrict__ src,
                                               float* __restrict__ dst, int n) {
    int i = blockIdx.x * 256 + threadIdx.x;
    if (i < n) dst[i] = src[i];
}

__global__ __launch_bounds__(256) void softmax_kernel(float* __restrict__ out) {
    __shared__ float redm[4];
    __shared__ float reds[4];
    softmax_row(out + (size_t)blockIdx.x * VOCAB, threadIdx.x, redm, reds);
}

extern "C" void kernel_launch(void* const* d_in, const int* in_sizes, int n_in,
                              void* d_out, int out_size, void* d_ws, size_t ws_size,
                              hipStream_t stream) {
    const int*   input    = (const int*)  d_in[0];
    const float* enc_emb  = (const float*)d_in[1];
    const float* enc_Wih  = (const float*)d_in[2];
    const float* enc_Whh  = (const float*)d_in[3];
    const float* enc_bih  = (const float*)d_in[4];
    const float* enc_bhh  = (const float*)d_in[5];
    const float* dec_emb  = (const float*)d_in[6];
    const float* dec_Wih  = (const float*)d_in[7];
    const float* dec_Whh  = (const float*)d_in[8];
    const float* dec_bih  = (const float*)d_in[9];
    const float* dec_bhh  = (const float*)d_in[10];
    const float* out_W    = (const float*)d_in[11];
    const float* out_b    = (const float*)d_in[12];

    float* out = (float*)d_out;
    char*  ws  = (char*)d_ws;

    float* hglob   = (float*)ws;                     // 131072 B
    u64*   pk      = (u64*)(ws + 131072);            // 65536 B
    u32*   hslot   = (u32*)(ws + 196608);            // 16384 B (128 lines)
    u64*   tokline = (u64*)(ws + 212992);            // 4096 B (32 lines)

    init_kernel<<<dim3(64), dim3(256), 0, stream>>>(hglob, hslot,
                                                    (u32*)pk, (u32*)tokline);

    void* args[] = {
        (void*)&input, (void*)&enc_emb, (void*)&enc_Wih, (void*)&enc_Whh,
        (void*)&enc_bih, (void*)&enc_bhh,
        (void*)&dec_emb, (void*)&dec_Wih, (void*)&dec_Whh, (void*)&dec_bih,
        (void*)&dec_bhh, (void*)&out_W, (void*)&out_b,
        (void*)&out, (void*)&hglob, (void*)&pk,
        (void*)&hslot, (void*)&tokline
    };
    hipError_t rc = hipLaunchCooperativeKernel((void*)seq2seq_main,
                                               dim3(NBLK), dim3(NTHR),
                                               args, 0, stream);
    if (rc != hipSuccess) {
        // fallback: multi-kernel path (kernel boundaries provide ordering)
        float* hb[2] = { hglob, hglob + BATCH * HDIM };
        for (int t = 0; t < SEQ; ++t) {
            gru_step_fb<<<dim3(128), dim3(256), 0, stream>>>(
                hb[t & 1], hb[(t + 1) & 1],
                enc_Wih, enc_Whh, enc_bih, enc_bhh, enc_emb, input, t, nullptr);
        }
        for (int t = 0; t < SEQ; ++t) {
            gru_step_fb<<<dim3(128), dim3(256), 0, stream>>>(
                hb[t & 1], hb[(t + 1) & 1],
                dec_Wih, dec_Whh, dec_bih, dec_bhh, dec_emb, nullptr, t, pk);
            logits_fb<<<dim3(NBLK), dim3(256), 0, stream>>>(
                hb[(t + 1) & 1], out_W, out_b, out, t, pk);
        }
        copy_fb<<<dim3((BATCH * HDIM + 255) / 256), dim3(256), 0, stream>>>(
            hglob, out + (size_t)BATCH * SEQ * VOCAB, BATCH * HDIM);
    }

    softmax_kernel<<<dim3(BATCH * SEQ), dim3(256), 0, stream>>>(out);
}